// Round 18
// baseline (521.377 us; speedup 1.0000x reference)
//
#include <hip/hip_runtime.h>

#define N_NODES 100000
#define N_EDGES 1600000
#define N_GRAPHS 256
#define F_IN 32
#define F_HID 64
#define F_OUT 64

#define FL_BLOCKS 6250          // 6250 blocks x 4 waves x 4 nodes = 100000 exactly
#define NXCD 8
#define DPX ((N_NODES + NXCD - 1) / NXCD)

// ---------------- CSR build ----------------
__global__ __launch_bounds__(256) void histogram_xcd(const int* __restrict__ dst,
                                                     int* __restrict__ deg) {
    int xcd = blockIdx.x & (NXCD - 1);
    int sub = blockIdx.x >> 3;
    int nsub = gridDim.x >> 3;
    int d_lo = xcd * DPX;
    int d_hi = min(d_lo + DPX, N_NODES);
    for (int e = sub * blockDim.x + threadIdx.x; e < N_EDGES; e += nsub * blockDim.x) {
        int d = __builtin_nontemporal_load(dst + e);
        if (d >= d_lo && d < d_hi) atomicAdd(&deg[d], 1);
    }
}

__global__ void scan1(const int* __restrict__ deg, int* __restrict__ end_, int* __restrict__ partials) {
    __shared__ int s[256];
    int tid = threadIdx.x;
    int i = blockIdx.x * 256 + tid;
    int v = (i < N_NODES) ? deg[i] : 0;
    s[tid] = v;
    __syncthreads();
#pragma unroll
    for (int off = 1; off < 256; off <<= 1) {
        int t = 0;
        if (tid >= off) t = s[tid - off];
        __syncthreads();
        if (tid >= off) s[tid] += t;
        __syncthreads();
    }
    if (i < N_NODES) end_[i] = s[tid];
    if (tid == 255) partials[blockIdx.x] = s[255];
}

__global__ void scan2(int* __restrict__ partials, int nb) {
    __shared__ int s[512];
    int tid = threadIdx.x;
    int v = (tid < nb) ? partials[tid] : 0;
    s[tid] = v;
    __syncthreads();
#pragma unroll
    for (int off = 1; off < 512; off <<= 1) {
        int t = 0;
        if (tid >= off) t = s[tid - off];
        __syncthreads();
        if (tid >= off) s[tid] += t;
        __syncthreads();
    }
    int excl = (tid > 0) ? s[tid - 1] : 0;
    if (tid < nb) partials[tid] = excl;
}

__global__ void scan3(const int* __restrict__ deg, int* __restrict__ end_,
                      int* __restrict__ cursor, const int* __restrict__ partials) {
    int i = blockIdx.x * 256 + threadIdx.x;
    if (i < N_NODES) {
        int e = end_[i] + partials[blockIdx.x];
        end_[i] = e;
        cursor[i] = e - deg[i];
    }
}

__global__ __launch_bounds__(256) void fill_adj_xcd(const int* __restrict__ src,
                                                    const int* __restrict__ dst,
                                                    int* __restrict__ cursor,
                                                    int* __restrict__ adj) {
    int xcd = blockIdx.x & (NXCD - 1);
    int sub = blockIdx.x >> 3;
    int nsub = gridDim.x >> 3;
    int d_lo = xcd * DPX;
    int d_hi = min(d_lo + DPX, N_NODES);
    for (int e = sub * blockDim.x + threadIdx.x; e < N_EDGES; e += nsub * blockDim.x) {
        int d = __builtin_nontemporal_load(dst + e);
        if (d >= d_lo && d < d_hi) {
            int pos = atomicAdd(&cursor[d], 1);
            adj[pos] = __builtin_nontemporal_load(src + e);
        }
    }
}

// SALU broadcast of a float from a known lane
__device__ __forceinline__ float rdlane(float v, int l) {
    return __int_as_float(__builtin_amdgcn_readlane(__float_as_int(v), l));
}

// ------- fused gather + transform (+pool), M=4 nodes per wave -------
// Gather: lane=(r,q), float4 loads, xor-butterfly -> every lane holds the full
// agg quad q of each node. Transform: per k, ONE pair of coalesced weight loads
// (L1) serves 4 nodes' FMAs (weight bytes/node cut 4x vs R17); row values come
// from registers via v_readlane (SALU broadcast, no DS traffic).
template <int FIN, bool POOL>
__global__ __launch_bounds__(256) void fused_m4(
        const float* __restrict__ hin,
        const int* __restrict__ adj, const int* __restrict__ end_, const int* __restrict__ deg,
        const float* __restrict__ Wrel, const float* __restrict__ brel,
        const float* __restrict__ Wroot,
        float* __restrict__ hout,
        const int* __restrict__ batch,
        float* __restrict__ sums) {
    constexpr int NQ = FIN / 4;       // 8 (FIN=32) or 16 (FIN=64)
    constexpr int R = 64 / NQ;        // 8 or 4
    const int lane = threadIdx.x & 63;
    const int wid = blockIdx.x * 4 + (threadIdx.x >> 6);
    const int n0 = wid * 4;
    if (n0 >= N_NODES) return;
    const int q = lane & (NQ - 1);
    const int r = lane / NQ;
    const float4* h4 = (const float4*)hin;

    float ax[4], ay[4], az[4], aw[4];
    float4 xv[4];

#pragma unroll
    for (int m = 0; m < 4; ++m) {
        int node = n0 + m;
        float sx = 0.f, sy = 0.f, sz = 0.f, sw = 0.f;
        if (node < N_NODES) {
            int e = end_[node];
            int d = deg[node];
            int s = e - d;
            for (int base = 0; base < d; base += 2 * R) {
                int i0 = base + r;
                int i1 = base + R + r;
                if (i0 < d) {
                    int sn = adj[s + i0];
                    float4 v = h4[(size_t)sn * NQ + q];
                    sx += v.x; sy += v.y; sz += v.z; sw += v.w;
                }
                if (i1 < d) {
                    int sn = adj[s + i1];
                    float4 v = h4[(size_t)sn * NQ + q];
                    sx += v.x; sy += v.y; sz += v.z; sw += v.w;
                }
            }
        }
        // butterfly: every lane ends with the full agg quad q
#pragma unroll
        for (int off = NQ; off < 64; off <<= 1) {
            sx += __shfl_xor(sx, off);
            sy += __shfl_xor(sy, off);
            sz += __shfl_xor(sz, off);
            sw += __shfl_xor(sw, off);
        }
        ax[m] = sx; ay[m] = sy; az[m] = sz; aw[m] = sw;
        xv[m] = (node < N_NODES) ? h4[(size_t)node * NQ + q]
                                 : make_float4(0.f, 0.f, 0.f, 0.f);
    }

    float bb = brel[lane];
    float o[4] = {bb, bb, bb, bb};
#pragma unroll
    for (int k = 0; k < FIN; ++k) {
        float wr = Wrel[k * 64 + lane];
        float wo = Wroot[k * 64 + lane];
        const int kq = k >> 2;
        const int j = k & 3;
#pragma unroll
        for (int m = 0; m < 4; ++m) {
            float av = rdlane(j == 0 ? ax[m] : j == 1 ? ay[m] : j == 2 ? az[m] : aw[m], kq);
            float xvv = rdlane(j == 0 ? xv[m].x : j == 1 ? xv[m].y : j == 2 ? xv[m].z : xv[m].w, kq);
            o[m] += av * wr + xvv * wo;
        }
    }

    if (POOL) {
        float psum = 0.0f;
        int curg = batch[n0];
#pragma unroll
        for (int m = 0; m < 4; ++m) {
            int node = n0 + m;
            if (node < N_NODES) {
                float hv = tanhf(o[m]);
                int g = batch[node];             // wave-uniform
                if (g != curg) {
                    atomicAdd(&sums[(size_t)curg * 64 + lane], psum);
                    psum = 0.0f;
                    curg = g;
                }
                psum += hv;
            }
        }
        atomicAdd(&sums[(size_t)curg * 64 + lane], psum);
    } else {
#pragma unroll
        for (int m = 0; m < 4; ++m) {
            int node = n0 + m;
            if (node < N_NODES) hout[(size_t)node * 64 + lane] = tanhf(o[m]);
        }
    }
}

__global__ void graph_counts(const int* __restrict__ batch, float* __restrict__ counts) {
    int g = threadIdx.x;
    if (g >= N_GRAPHS) return;
    int lo = 0, hi = N_NODES;
    while (lo < hi) { int mid = (lo + hi) >> 1; if (batch[mid] < g) lo = mid + 1; else hi = mid; }
    int start = lo;
    lo = 0; hi = N_NODES;
    while (lo < hi) { int mid = (lo + hi) >> 1; if (batch[mid] <= g) lo = mid + 1; else hi = mid; }
    counts[g] = (float)(lo - start);
}

__global__ void finalize(const float* __restrict__ sums,
                         const float* __restrict__ counts,
                         float* __restrict__ out) {
    int i = blockIdx.x * blockDim.x + threadIdx.x;
    if (i < N_GRAPHS * 64) {
        float c = counts[i >> 6];
        out[i] = sums[i] / fmaxf(c, 1.0f);
    }
}

extern "C" void kernel_launch(void* const* d_in, const int* in_sizes, int n_in,
                              void* d_out, int out_size, void* d_ws, size_t ws_size,
                              hipStream_t stream) {
    const float* x       = (const float*)d_in[0];
    const int*   ei      = (const int*)d_in[1];
    const int*   batch   = (const int*)d_in[2];
    const float* W1_rel  = (const float*)d_in[3];
    const float* b1_rel  = (const float*)d_in[4];
    const float* W1_root = (const float*)d_in[5];
    const float* W2_rel  = (const float*)d_in[6];
    const float* b2_rel  = (const float*)d_in[7];
    const float* W2_root = (const float*)d_in[8];
    float* out = (float*)d_out;

    const int* src = ei;
    const int* dst = ei + N_EDGES;

    // ---- workspace layout (bytes) ----
    char* ws = (char*)d_ws;
    int*   deg      = (int*)(ws + 0);                 // 400000
    float* sums     = (float*)(ws + 400000);          // 65536
    float* counts   = (float*)(ws + 465536);          // 1024
    // ---- zero boundary: 466560 ----
    int*   end_     = (int*)(ws + 466560);            // 400000
    int*   cursor   = (int*)(ws + 866560);            // 400000
    int*   partials = (int*)(ws + 1266560);           // 2048
    int*   adj      = (int*)(ws + 1268608);           // 6400000
    float* h1       = (float*)(ws + 7668608);         // 25600000

    hipMemsetAsync(d_ws, 0, 466560, stream);

    // ---- CSR build ----
    const int NB_NODE = (N_NODES + 255) / 256;
    histogram_xcd<<<2048, 256, 0, stream>>>(dst, deg);
    scan1<<<NB_NODE, 256, 0, stream>>>(deg, end_, partials);
    scan2<<<1, 512, 0, stream>>>(partials, NB_NODE);
    scan3<<<NB_NODE, 256, 0, stream>>>(deg, end_, cursor, partials);
    fill_adj_xcd<<<2048, 256, 0, stream>>>(src, dst, cursor, adj);

    // ---- fused layers (4 nodes/wave) ----
    fused_m4<F_IN, false><<<FL_BLOCKS, 256, 0, stream>>>(
        x, adj, end_, deg, W1_rel, b1_rel, W1_root, h1, nullptr, nullptr);
    fused_m4<F_HID, true><<<FL_BLOCKS, 256, 0, stream>>>(
        h1, adj, end_, deg, W2_rel, b2_rel, W2_root, nullptr, batch, sums);

    graph_counts<<<1, 256, 0, stream>>>(batch, counts);
    finalize<<<(N_GRAPHS * 64 + 255) / 256, 256, 0, stream>>>(sums, counts, out);
}

// Round 19
// 391.770 us; speedup vs baseline: 1.3308x; 1.3308x over previous
//
#include <hip/hip_runtime.h>

#define N_NODES 100000
#define N_EDGES 1600000
#define N_GRAPHS 256
#define F_IN 32
#define F_HID 64
#define F_OUT 64

#define NXCD 8
#define DPX ((N_NODES + NXCD - 1) / NXCD)

// ---------------- CSR build ----------------
__global__ __launch_bounds__(256) void histogram_xcd(const int* __restrict__ dst,
                                                     int* __restrict__ deg) {
    int xcd = blockIdx.x & (NXCD - 1);
    int sub = blockIdx.x >> 3;
    int nsub = gridDim.x >> 3;
    int d_lo = xcd * DPX;
    int d_hi = min(d_lo + DPX, N_NODES);
    for (int e = sub * blockDim.x + threadIdx.x; e < N_EDGES; e += nsub * blockDim.x) {
        int d = __builtin_nontemporal_load(dst + e);
        if (d >= d_lo && d < d_hi) atomicAdd(&deg[d], 1);
    }
}

__global__ void scan1(const int* __restrict__ deg, int* __restrict__ end_, int* __restrict__ partials) {
    __shared__ int s[256];
    int tid = threadIdx.x;
    int i = blockIdx.x * 256 + tid;
    int v = (i < N_NODES) ? deg[i] : 0;
    s[tid] = v;
    __syncthreads();
#pragma unroll
    for (int off = 1; off < 256; off <<= 1) {
        int t = 0;
        if (tid >= off) t = s[tid - off];
        __syncthreads();
        if (tid >= off) s[tid] += t;
        __syncthreads();
    }
    if (i < N_NODES) end_[i] = s[tid];
    if (tid == 255) partials[blockIdx.x] = s[255];
}

__global__ void scan2(int* __restrict__ partials, int nb) {
    __shared__ int s[512];
    int tid = threadIdx.x;
    int v = (tid < nb) ? partials[tid] : 0;
    s[tid] = v;
    __syncthreads();
#pragma unroll
    for (int off = 1; off < 512; off <<= 1) {
        int t = 0;
        if (tid >= off) t = s[tid - off];
        __syncthreads();
        if (tid >= off) s[tid] += t;
        __syncthreads();
    }
    int excl = (tid > 0) ? s[tid - 1] : 0;
    if (tid < nb) partials[tid] = excl;
}

__global__ void scan3(const int* __restrict__ deg, int* __restrict__ end_,
                      int* __restrict__ cursor, const int* __restrict__ partials) {
    int i = blockIdx.x * 256 + threadIdx.x;
    if (i < N_NODES) {
        int e = end_[i] + partials[blockIdx.x];
        end_[i] = e;
        cursor[i] = e - deg[i];
    }
}

__global__ __launch_bounds__(256) void fill_adj_xcd(const int* __restrict__ src,
                                                    const int* __restrict__ dst,
                                                    int* __restrict__ cursor,
                                                    int* __restrict__ adj) {
    int xcd = blockIdx.x & (NXCD - 1);
    int sub = blockIdx.x >> 3;
    int nsub = gridDim.x >> 3;
    int d_lo = xcd * DPX;
    int d_hi = min(d_lo + DPX, N_NODES);
    for (int e = sub * blockDim.x + threadIdx.x; e < N_EDGES; e += nsub * blockDim.x) {
        int d = __builtin_nontemporal_load(dst + e);
        if (d >= d_lo && d < d_hi) {
            int pos = atomicAdd(&cursor[d], 1);
            adj[pos] = __builtin_nontemporal_load(src + e);
        }
    }
}

// ---------------- gathers, ILP-4 (4 row loads in flight) ----------------
__global__ __launch_bounds__(256) void gather64_v3(const float* __restrict__ h,
        const int* __restrict__ adj, const int* __restrict__ end_, const int* __restrict__ deg,
        float* __restrict__ agg) {
    int node = (blockIdx.x * blockDim.x + threadIdx.x) >> 6;
    int lane = threadIdx.x & 63;
    if (node >= N_NODES) return;
    int e = end_[node];
    int d = deg[node];
    int s = e - d;
    int q = lane & 15;
    int r = lane >> 4;                 // 4 rows in flight per chunk
    const float4* h4 = (const float4*)h;

    float ax = 0.f, ay = 0.f, az = 0.f, aw = 0.f;
    int base = 0;
    for (; base + 16 <= d; base += 16) {
        int s0 = adj[s + base + r];
        int s1 = adj[s + base + 4 + r];
        int s2 = adj[s + base + 8 + r];
        int s3 = adj[s + base + 12 + r];
        float4 v0 = h4[(size_t)s0 * 16 + q];
        float4 v1 = h4[(size_t)s1 * 16 + q];
        float4 v2 = h4[(size_t)s2 * 16 + q];
        float4 v3 = h4[(size_t)s3 * 16 + q];
        ax += v0.x + v1.x + v2.x + v3.x;
        ay += v0.y + v1.y + v2.y + v3.y;
        az += v0.z + v1.z + v2.z + v3.z;
        aw += v0.w + v1.w + v2.w + v3.w;
    }
    for (; base < d; base += 4) {
        int i = base + r;
        if (i < d) {
            int sn = adj[s + i];
            float4 v = h4[(size_t)sn * 16 + q];
            ax += v.x; ay += v.y; az += v.z; aw += v.w;
        }
    }
#pragma unroll
    for (int off = 16; off < 64; off <<= 1) {
        ax += __shfl_xor(ax, off);
        ay += __shfl_xor(ay, off);
        az += __shfl_xor(az, off);
        aw += __shfl_xor(aw, off);
    }
    if (r == 0) {
        float4 o; o.x = ax; o.y = ay; o.z = az; o.w = aw;
        ((float4*)agg)[(size_t)node * 16 + q] = o;
    }
}

__global__ __launch_bounds__(256) void gather32_v3(const float* __restrict__ xin,
        const int* __restrict__ adj, const int* __restrict__ end_, const int* __restrict__ deg,
        float* __restrict__ agg) {
    int node = (blockIdx.x * blockDim.x + threadIdx.x) >> 6;
    int lane = threadIdx.x & 63;
    if (node >= N_NODES) return;
    int e = end_[node];
    int d = deg[node];
    int s = e - d;
    int q = lane & 7;
    int r = lane >> 3;                 // 8 rows in flight per chunk
    const float4* x4 = (const float4*)xin;

    float ax = 0.f, ay = 0.f, az = 0.f, aw = 0.f;
    int base = 0;
    for (; base + 32 <= d; base += 32) {
        int s0 = adj[s + base + r];
        int s1 = adj[s + base + 8 + r];
        int s2 = adj[s + base + 16 + r];
        int s3 = adj[s + base + 24 + r];
        float4 v0 = x4[(size_t)s0 * 8 + q];
        float4 v1 = x4[(size_t)s1 * 8 + q];
        float4 v2 = x4[(size_t)s2 * 8 + q];
        float4 v3 = x4[(size_t)s3 * 8 + q];
        ax += v0.x + v1.x + v2.x + v3.x;
        ay += v0.y + v1.y + v2.y + v3.y;
        az += v0.z + v1.z + v2.z + v3.z;
        aw += v0.w + v1.w + v2.w + v3.w;
    }
    for (; base < d; base += 8) {
        int i = base + r;
        if (i < d) {
            int sn = adj[s + i];
            float4 v = x4[(size_t)sn * 8 + q];
            ax += v.x; ay += v.y; az += v.z; aw += v.w;
        }
    }
#pragma unroll
    for (int off = 8; off < 64; off <<= 1) {
        ax += __shfl_xor(ax, off);
        ay += __shfl_xor(ay, off);
        az += __shfl_xor(az, off);
        aw += __shfl_xor(aw, off);
    }
    if (r == 0) {
        float4 o; o.x = ax; o.y = ay; o.z = az; o.w = aw;
        ((float4*)agg)[(size_t)node * 8 + q] = o;
    }
}

// ---------------- coalesced transforms ----------------
// Wave cooperatively loads 4 (FIN=64) or 8 (FIN=32) node rows with ONE 1024B
// coalesced float4 load (lane = row x quad), then broadcasts elements via
// v_readlane (compile-time lanes, straight-line) into per-lane column FMAs.
// No uniform-broadcast load stream, no node loop, nothing to remat or spill.

#define RD(v, l) __int_as_float(__builtin_amdgcn_readlane(__float_as_int(v), (l)))

#define TACC(oN, L) \
    oN += RD(va.x, (L)) * wr0 + RD(va.y, (L)) * wr1 + RD(va.z, (L)) * wr2 + RD(va.w, (L)) * wr3 \
        + RD(vx.x, (L)) * wo0 + RD(vx.y, (L)) * wo1 + RD(vx.z, (L)) * wo2 + RD(vx.w, (L)) * wo3;

#define TWTS(KQ) \
    float wr0 = Wrel[(4 * (KQ) + 0) * 64 + lane], wr1 = Wrel[(4 * (KQ) + 1) * 64 + lane], \
          wr2 = Wrel[(4 * (KQ) + 2) * 64 + lane], wr3 = Wrel[(4 * (KQ) + 3) * 64 + lane]; \
    float wo0 = Wroot[(4 * (KQ) + 0) * 64 + lane], wo1 = Wroot[(4 * (KQ) + 1) * 64 + lane], \
          wo2 = Wroot[(4 * (KQ) + 2) * 64 + lane], wo3 = Wroot[(4 * (KQ) + 3) * 64 + lane];

// transform1: FIN=32 (8 quads/row, 8 rows/wave). 12500 waves = 3125 blocks.
#define T1Q(KQ) { TWTS(KQ) \
    TACC(o0, (KQ)) TACC(o1, 8 + (KQ)) TACC(o2, 16 + (KQ)) TACC(o3, 24 + (KQ)) \
    TACC(o4, 32 + (KQ)) TACC(o5, 40 + (KQ)) TACC(o6, 48 + (KQ)) TACC(o7, 56 + (KQ)) }

__global__ __launch_bounds__(256) void transform1_c(const float* __restrict__ agg,
        const float* __restrict__ xin,
        const float* __restrict__ Wrel, const float* __restrict__ brel,
        const float* __restrict__ Wroot,
        float* __restrict__ h1) {
    int lane = threadIdx.x & 63;
    int wid = blockIdx.x * 4 + (threadIdx.x >> 6);
    int n0 = wid * 8;                          // 100000 = 12500*8, exact
    if (n0 >= N_NODES) return;
    float4 va = ((const float4*)(agg + (size_t)n0 * 32))[lane];  // row lane>>3, quad lane&7
    float4 vx = ((const float4*)(xin + (size_t)n0 * 32))[lane];
    float bb = brel[lane];
    float o0 = bb, o1 = bb, o2 = bb, o3 = bb, o4 = bb, o5 = bb, o6 = bb, o7 = bb;

    T1Q(0) T1Q(1) T1Q(2) T1Q(3) T1Q(4) T1Q(5) T1Q(6) T1Q(7)

    float* H = h1 + (size_t)n0 * 64 + lane;
    H[0 * 64] = tanhf(o0); H[1 * 64] = tanhf(o1); H[2 * 64] = tanhf(o2); H[3 * 64] = tanhf(o3);
    H[4 * 64] = tanhf(o4); H[5 * 64] = tanhf(o5); H[6 * 64] = tanhf(o6); H[7 * 64] = tanhf(o7);
}

// transform2+pool: FIN=64 (16 quads/row, 4 rows/wave). 25000 waves = 6250 blocks.
#define T2Q(KQ) { TWTS(KQ) \
    TACC(o0, (KQ)) TACC(o1, 16 + (KQ)) TACC(o2, 32 + (KQ)) TACC(o3, 48 + (KQ)) }

__global__ __launch_bounds__(256) void transform2_pool_c(const float* __restrict__ agg,
        const float* __restrict__ h1,
        const float* __restrict__ Wrel, const float* __restrict__ brel,
        const float* __restrict__ Wroot,
        const int* __restrict__ batch,
        float* __restrict__ sums) {
    int lane = threadIdx.x & 63;
    int wid = blockIdx.x * 4 + (threadIdx.x >> 6);
    int n0 = wid * 4;                          // 100000 = 25000*4, exact
    if (n0 >= N_NODES) return;
    float4 va = ((const float4*)(agg + (size_t)n0 * 64))[lane]; // row lane>>4, quad lane&15
    float4 vx = ((const float4*)(h1 + (size_t)n0 * 64))[lane];
    float bb = brel[lane];
    float o0 = bb, o1 = bb, o2 = bb, o3 = bb;

    T2Q(0) T2Q(1) T2Q(2) T2Q(3) T2Q(4) T2Q(5) T2Q(6) T2Q(7)
    T2Q(8) T2Q(9) T2Q(10) T2Q(11) T2Q(12) T2Q(13) T2Q(14) T2Q(15)

    float t0 = tanhf(o0), t1 = tanhf(o1), t2 = tanhf(o2), t3 = tanhf(o3);
    int g0 = batch[n0 + 0], g1 = batch[n0 + 1], g2 = batch[n0 + 2], g3 = batch[n0 + 3];

    float psum = t0;
    int curg = g0;
    if (g1 != curg) { atomicAdd(&sums[(size_t)curg * 64 + lane], psum); psum = 0.f; curg = g1; }
    psum += t1;
    if (g2 != curg) { atomicAdd(&sums[(size_t)curg * 64 + lane], psum); psum = 0.f; curg = g2; }
    psum += t2;
    if (g3 != curg) { atomicAdd(&sums[(size_t)curg * 64 + lane], psum); psum = 0.f; curg = g3; }
    psum += t3;
    atomicAdd(&sums[(size_t)curg * 64 + lane], psum);
}

__global__ void graph_counts(const int* __restrict__ batch, float* __restrict__ counts) {
    int g = threadIdx.x;
    if (g >= N_GRAPHS) return;
    int lo = 0, hi = N_NODES;
    while (lo < hi) { int mid = (lo + hi) >> 1; if (batch[mid] < g) lo = mid + 1; else hi = mid; }
    int start = lo;
    lo = 0; hi = N_NODES;
    while (lo < hi) { int mid = (lo + hi) >> 1; if (batch[mid] <= g) lo = mid + 1; else hi = mid; }
    counts[g] = (float)(lo - start);
}

__global__ void finalize(const float* __restrict__ sums,
                         const float* __restrict__ counts,
                         float* __restrict__ out) {
    int i = blockIdx.x * blockDim.x + threadIdx.x;
    if (i < N_GRAPHS * 64) {
        float c = counts[i >> 6];
        out[i] = sums[i] / fmaxf(c, 1.0f);
    }
}

extern "C" void kernel_launch(void* const* d_in, const int* in_sizes, int n_in,
                              void* d_out, int out_size, void* d_ws, size_t ws_size,
                              hipStream_t stream) {
    const float* x       = (const float*)d_in[0];
    const int*   ei      = (const int*)d_in[1];
    const int*   batch   = (const int*)d_in[2];
    const float* W1_rel  = (const float*)d_in[3];
    const float* b1_rel  = (const float*)d_in[4];
    const float* W1_root = (const float*)d_in[5];
    const float* W2_rel  = (const float*)d_in[6];
    const float* b2_rel  = (const float*)d_in[7];
    const float* W2_root = (const float*)d_in[8];
    float* out = (float*)d_out;

    const int* src = ei;
    const int* dst = ei + N_EDGES;

    // ---- workspace layout (bytes) ----
    char* ws = (char*)d_ws;
    int*   deg      = (int*)(ws + 0);                 // 400000
    float* sums     = (float*)(ws + 400000);          // 65536
    float* counts   = (float*)(ws + 465536);          // 1024
    // ---- zero boundary: 466560 ----
    int*   end_     = (int*)(ws + 466560);            // 400000
    int*   cursor   = (int*)(ws + 866560);            // 400000
    int*   partials = (int*)(ws + 1266560);           // 2048
    int*   adj      = (int*)(ws + 1268608);           // 6400000
    float* aggbuf   = (float*)(ws + 7668608);         // 25600000 (agg1/agg2 shared)
    float* h1       = (float*)(ws + 33268608);        // 25600000

    hipMemsetAsync(d_ws, 0, 466560, stream);

    // ---- CSR build ----
    const int NB_NODE = (N_NODES + 255) / 256;
    histogram_xcd<<<2048, 256, 0, stream>>>(dst, deg);
    scan1<<<NB_NODE, 256, 0, stream>>>(deg, end_, partials);
    scan2<<<1, 512, 0, stream>>>(partials, NB_NODE);
    scan3<<<NB_NODE, 256, 0, stream>>>(deg, end_, cursor, partials);
    fill_adj_xcd<<<2048, 256, 0, stream>>>(src, dst, cursor, adj);

    // ---- layer 1 ----
    gather32_v3<<<(N_NODES * 64 + 255) / 256, 256, 0, stream>>>(x, adj, end_, deg, aggbuf);
    transform1_c<<<3125, 256, 0, stream>>>(aggbuf, x, W1_rel, b1_rel, W1_root, h1);

    // ---- layer 2 ----
    gather64_v3<<<(N_NODES * 64 + 255) / 256, 256, 0, stream>>>(h1, adj, end_, deg, aggbuf);
    transform2_pool_c<<<6250, 256, 0, stream>>>(aggbuf, h1, W2_rel, b2_rel, W2_root, batch, sums);

    graph_counts<<<1, 256, 0, stream>>>(batch, counts);
    finalize<<<(N_GRAPHS * 64 + 255) / 256, 256, 0, stream>>>(sums, counts, out);
}